// Round 6
// baseline (710.233 us; speedup 1.0000x reference)
//
#include <hip/hip_runtime.h>
#include <cstdint>
#include <cstddef>

typedef unsigned short u16;
using f16x8 = __attribute__((ext_vector_type(8))) _Float16;
using f32x4 = __attribute__((ext_vector_type(4))) float;
using u16x4 = __attribute__((ext_vector_type(4))) unsigned short;

__device__ __forceinline__ u16 f2h(float f) {
  union { _Float16 h; u16 u; } c;
  c.h = (_Float16)f;
  return c.u;
}

// async global->LDS, 16B per lane. LDS dest = wave-uniform base + lane*16.
__device__ __forceinline__ void gl_lds16(const void* g, void* lds) {
  __builtin_amdgcn_global_load_lds(
      (const __attribute__((address_space(1))) void*)(uintptr_t)g,
      (__attribute__((address_space(3))) void*)(uint32_t)(uintptr_t)lds,
      16, 0, 0);
}

// LDS chunk swizzle: slot chunk q of row r holds global chunk q ^ ((r>>1)&3).
// Frag read of logical chunk `quad` from row (16a + lm) -> physical chunk
// quad ^ ((lm>>1)&3): 2-way (free) bank access on 64B-stride rows.

// ---------------------------------------------------------------------------
// bt-GEMM: C[m,n] = sum_k A[m,k]*Bt[n,k], fp16. 128x128 tile, BK=32, 4 waves.
// MODE 0: fp16 out (+bias if non-null). MODE 3: fp16 out + bias + transposed
// copy to hTp laid out [batch(row>>11)][col][row&2047].
// ---------------------------------------------------------------------------
template <int MODE>
__global__ __launch_bounds__(256) void gemm_bt(
    const u16* __restrict__ A, const u16* __restrict__ Bt,
    u16* __restrict__ C, const float* __restrict__ bias,
    u16* __restrict__ hTp, int Ncols, int K)
{
  __shared__ __align__(16) u16 sA[128 * 32];
  __shared__ __align__(16) u16 sB[128 * 32];

  const int m0 = blockIdx.y * 128;
  const int n0 = blockIdx.x * 128;
  const int t    = threadIdx.x;
  const int lane = t & 63;
  const int wave = t >> 6;
  const int wm   = (wave >> 1) * 64;
  const int wn   = (wave & 1) * 64;
  const int lm   = lane & 15;
  const int quad = lane >> 4;
  const int sw   = (quad ^ ((lm >> 1) & 3)) * 8;

  f32x4 acc[4][4];
#pragma unroll
  for (int i = 0; i < 4; ++i)
#pragma unroll
    for (int j = 0; j < 4; ++j) acc[i][j] = f32x4{0.f, 0.f, 0.f, 0.f};

  const int r0 = t >> 2,         c0 = t & 3;
  const int r1 = (t + 256) >> 2;
  const int g0 = c0 ^ ((r0 >> 1) & 3);
  const int g1 = c0 ^ ((r1 >> 1) & 3);
  const int ldsb0 = (t & ~63) * 8;
  const int ldsb1 = ((t & ~63) + 256) * 8;

  const int nk = K >> 5;
  for (int kc = 0; kc < nk; ++kc) {
    const int kb = kc * 32;
    gl_lds16(A  + (size_t)(m0 + r0) * K + kb + g0 * 8, sA + ldsb0);
    gl_lds16(A  + (size_t)(m0 + r1) * K + kb + g1 * 8, sA + ldsb1);
    gl_lds16(Bt + (size_t)(n0 + r0) * K + kb + g0 * 8, sB + ldsb0);
    gl_lds16(Bt + (size_t)(n0 + r1) * K + kb + g1 * 8, sB + ldsb1);
    __syncthreads();

    f16x8 af[4], bf[4];
#pragma unroll
    for (int i = 0; i < 4; ++i) {
      af[i] = *(const f16x8*)(sA + (wm + i * 16 + lm) * 32 + sw);
      bf[i] = *(const f16x8*)(sB + (wn + i * 16 + lm) * 32 + sw);
    }
#pragma unroll
    for (int i = 0; i < 4; ++i)
#pragma unroll
      for (int j = 0; j < 4; ++j)
        acc[i][j] = __builtin_amdgcn_mfma_f32_16x16x32_f16(af[i], bf[j], acc[i][j], 0, 0, 0);
    __syncthreads();
  }

  // C/D layout: col=lane&15, row=quad*4+reg  [m89-verified]
#pragma unroll
  for (int j = 0; j < 4; ++j) {
    const int col = n0 + wn + j * 16 + lm;
    const float bv = bias ? bias[col] : 0.f;
#pragma unroll
    for (int i = 0; i < 4; ++i) {
      const int row0 = m0 + wm + i * 16 + quad * 4;
      u16x4 tp;
#pragma unroll
      for (int r = 0; r < 4; ++r) {
        const u16 hv = f2h(acc[i][j][r] + bv);
        C[(size_t)(row0 + r) * Ncols + col] = hv;
        tp[r] = hv;
      }
      if (MODE == 3) {
        const int b = row0 >> 11, n = row0 & 2047;
        *(u16x4*)(hTp + ((size_t)b * 512 + col) * 2048 + n) = tp;
      }
    }
  }
}

// ---------------------------------------------------------------------------
// Flash-fused S=ha.h^T -> masked online softmax -> O=P.h -> elu(O/l)
// Block: 512 thr (8 waves), 32 Q-rows, one batch. Grid 512 = 2 blocks/CU
// = 16 waves/CU = 4 waves/SIMD. Staging tile: 160 rows (128 K + 32 Q) x 64 k,
// double-buffered (2 x 20KB). Softmax state in registers (no B3 barrier).
// QK: waves 2(row-group) x 4(col-group); PV: per-wave 64-wide d-slice.
// ---------------------------------------------------------------------------
__global__ __launch_bounds__(512, 4) void flash_gat(
    const u16* __restrict__ haP, const u16* __restrict__ hP,
    const u16* __restrict__ hTP, const u16* __restrict__ adjb,
    float* __restrict__ outP)
{
  __shared__ __align__(16) u16 sKQ[2 * 10240];   // 2 bufs x (2 panels x 160 rows x 32k)
  __shared__ __align__(16) u16 sP[32 * 136];     // 8.7 KB padded stride
  __shared__ __align__(16) float rmA2[32][4];
  __shared__ __align__(16) float rsA2[32][4];

  const int t     = threadIdx.x;
  const int batch = blockIdx.x & 7;              // batch -> XCD affinity
  const int q0    = (blockIdx.x >> 3) << 5;
  const int lane  = t & 63;
  const int wave  = t >> 6;
  const int lm    = lane & 15;
  const int quad  = lane >> 4;
  const int sw    = (quad ^ ((lm >> 1) & 3)) * 8;
  const int rg    = wave >> 2;                   // QK row-group (16 rows)
  const int cg    = wave & 3;                    // QK col-group (32 cols)
  const int wqm   = rg * 16;
  const int wqn   = cg * 32;
  const int wd    = wave * 64;                   // PV d-slice

  const u16* Q  = haP + ((size_t)batch * 2048 + q0) * 512;
  const u16* Kb = hP  + (size_t)batch * 2048 * 512;
  const u16* V  = hTP + (size_t)batch * 512 * 2048;
  const u16* Ar = adjb + ((size_t)batch * 2048 + q0) * 128;
  float* Co = outP + ((size_t)batch * 2048 + q0) * 512;

  // --- staging slot precompute: 1280 slots of 16B (160 rows x 64k), 3 per thr
  const u16* sbase[3]; size_t sntm[3]; u16* sdst[3]; bool sact[3];
#pragma unroll
  for (int c = 0; c < 3; ++c) {
    const int s = c * 512 + t;
    sact[c] = (s < 1280);
    const int q = s & 3, rr = s >> 2;
    const int p = (rr >= 160) ? 1 : 0;           // 32k-panel within stage
    const int r = rr - p * 160;                  // 0..159: K rows 0..127, Q rows 128..159
    const int g = q ^ ((r >> 1) & 3);
    const bool isQ = (r >= 128);
    sbase[c] = isQ ? (Q + (size_t)(r - 128) * 512 + p * 32 + g * 8)
                   : (Kb + (size_t)r * 512 + p * 32 + g * 8);
    sntm[c] = isQ ? 0 : (size_t)128 * 512;       // per-nt advance (K rows only)
    sdst[c] = sKQ + (size_t)(c * 512 + (t & ~63)) * 8;
  }

  auto stage = [&](int ntv, int kc, int d) {
    const size_t ko = (size_t)ntv * 0 + kc * 64; // k offset in u16
#pragma unroll
    for (int c = 0; c < 3; ++c)
      if (sact[c])
        gl_lds16(sbase[c] + sntm[c] * ntv + ko, sdst[c] + d * 10240);
  };

  // --- softmax state in registers (rows i*16 + quad*4 + r, replicated in lm)
  float m_[2][4], l_[2][4], al_[2][4];
#pragma unroll
  for (int i = 0; i < 2; ++i)
#pragma unroll
    for (int r = 0; r < 4; ++r) { m_[i][r] = -1e30f; l_[i][r] = 0.f; }

  f32x4 o[2][4];
#pragma unroll
  for (int i = 0; i < 2; ++i)
#pragma unroll
    for (int j = 0; j < 4; ++j) o[i][j] = f32x4{0.f, 0.f, 0.f, 0.f};

  stage(0, 0, 0);

  for (int nt = 0; nt < 16; ++nt) {
    const int n0 = nt * 128;
    f32x4 sacc[2];
    sacc[0] = f32x4{0.f, 0.f, 0.f, 0.f};
    sacc[1] = f32x4{0.f, 0.f, 0.f, 0.f};

    for (int kc = 0; kc < 8; ++kc) {
      __syncthreads();                            // drain stage(kc); fence buffer reuse
      if (kc < 7) stage(nt, kc + 1, (kc + 1) & 1);
      const int b0 = (kc & 1) * 10240;
#pragma unroll
      for (int kk = 0; kk < 2; ++kk) {
        const int pb = b0 + kk * 5120;
        const f16x8 aq = *(const f16x8*)(sKQ + pb + (128 + wqm + lm) * 32 + sw);
        const f16x8 bk0 = *(const f16x8*)(sKQ + pb + (wqn + lm) * 32 + sw);
        const f16x8 bk1 = *(const f16x8*)(sKQ + pb + (wqn + 16 + lm) * 32 + sw);
        sacc[0] = __builtin_amdgcn_mfma_f32_16x16x32_f16(aq, bk0, sacc[0], 0, 0, 0);
        sacc[1] = __builtin_amdgcn_mfma_f32_16x16x32_f16(aq, bk1, sacc[1], 0, 0, 0);
      }
    }

    // ---- mask + per-wave row max (C-layout: row=quad*4+r, col=lane&15) ----
    const int awoff = nt * 8 + (wqn >> 4);
#pragma unroll
    for (int r = 0; r < 4; ++r) {
      const int R = wqm + quad * 4 + r;
      const unsigned w = *(const unsigned*)(Ar + (size_t)R * 128 + awoff);
      float s0 = ((w >> lm) & 1u) ? sacc[0][r] : -1e30f;
      float s1 = ((w >> (lm + 16)) & 1u) ? sacc[1][r] : -1e30f;
      sacc[0][r] = s0; sacc[1][r] = s1;
      float mx = fmaxf(s0, s1);
      mx = fmaxf(mx, __shfl_xor(mx, 1));
      mx = fmaxf(mx, __shfl_xor(mx, 2));
      mx = fmaxf(mx, __shfl_xor(mx, 4));
      mx = fmaxf(mx, __shfl_xor(mx, 8));
      if (lm == 0) rmA2[R][cg] = mx;
    }
    __syncthreads();  // B1: rmA ready; all sKQ reads complete

    // ---- exp + P~ to LDS + per-wave row sums ----
#pragma unroll
    for (int r = 0; r < 4; ++r) {
      const int R = wqm + quad * 4 + r;
      const f32x4 rm = *(const f32x4*)rmA2[R];
      const float cm = fmaxf(fmaxf(rm[0], rm[1]), fmaxf(rm[2], rm[3]));
      const float mold = rg ? m_[1][r] : m_[0][r];
      const float nm = fmaxf(mold, cm);
      const float p0 = __expf(sacc[0][r] - nm);
      const float p1 = __expf(sacc[1][r] - nm);
      sP[R * 136 + wqn + lm]      = f2h(p0);
      sP[R * 136 + wqn + 16 + lm] = f2h(p1);
      float rs = p0 + p1;
      rs += __shfl_xor(rs, 1);
      rs += __shfl_xor(rs, 2);
      rs += __shfl_xor(rs, 4);
      rs += __shfl_xor(rs, 8);
      if (lm == 0) rsA2[R][cg] = rs;
    }
    __syncthreads();  // B2: rsA + sP ready

    // ---- state update, in registers, redundantly per wave (deterministic) --
#pragma unroll
    for (int i = 0; i < 2; ++i)
#pragma unroll
      for (int r = 0; r < 4; ++r) {
        const int R = i * 16 + quad * 4 + r;
        const f32x4 rm = *(const f32x4*)rmA2[R];
        const f32x4 rs = *(const f32x4*)rsA2[R];
        const float cm = fmaxf(fmaxf(rm[0], rm[1]), fmaxf(rm[2], rm[3]));
        const float cs = (rs[0] + rs[1]) + (rs[2] + rs[3]);
        const float nm = fmaxf(m_[i][r], cm);
        const float a  = __expf(m_[i][r] - nm);
        l_[i][r]  = a * l_[i][r] + cs;
        m_[i][r]  = nm;
        al_[i][r] = a;
      }

    // prefetch next nt's first K-stage; hidden under PV (no barriers below)
    stage((nt + 1) & 15, 0, 0);

    // ---- O rescale + PV (V-frags direct from global hT; line-covered) ----
#pragma unroll
    for (int i = 0; i < 2; ++i)
#pragma unroll
      for (int r = 0; r < 4; ++r) {
        const float a = al_[i][r];
#pragma unroll
        for (int j = 0; j < 4; ++j) o[i][j][r] *= a;
      }
#pragma unroll
    for (int kb = 0; kb < 4; ++kb) {
      f16x8 ap[2], bv[4];
#pragma unroll
      for (int i = 0; i < 2; ++i)
        ap[i] = *(const f16x8*)(sP + (i * 16 + lm) * 136 + kb * 32 + quad * 8);
#pragma unroll
      for (int j = 0; j < 4; ++j)
        bv[j] = *(const f16x8*)(V + (size_t)(wd + j * 16 + lm) * 2048 + n0 + kb * 32 + quad * 8);
#pragma unroll
      for (int i = 0; i < 2; ++i)
#pragma unroll
        for (int j = 0; j < 4; ++j)
          o[i][j] = __builtin_amdgcn_mfma_f32_16x16x32_f16(ap[i], bv[j], o[i][j], 0, 0, 0);
    }
  }

  // ---- epilogue: out = elu(O / l) ----
#pragma unroll
  for (int i = 0; i < 2; ++i)
#pragma unroll
    for (int r = 0; r < 4; ++r) {
      const int R = i * 16 + quad * 4 + r;
      const float inv = 1.f / l_[i][r];
#pragma unroll
      for (int j = 0; j < 4; ++j) {
        float v = o[i][j][r] * inv;
        v = v > 0.f ? v : expm1f(v);
        Co[(size_t)R * 512 + wd + j * 16 + lm] = v;
      }
    }
}

// ---------------------------------------------------------------------------
// adjacency -> bitmask: word i packs adj[i*16 .. i*16+16) (bit e = col e)
// ---------------------------------------------------------------------------
__global__ __launch_bounds__(256) void adj_pack(
    const int* __restrict__ adj, u16* __restrict__ outw, int nwords)
{
  const int i = blockIdx.x * 256 + threadIdx.x;
  if (i >= nwords) return;
  const int4* p = (const int4*)(adj + (size_t)i * 16);
  unsigned w = 0;
#pragma unroll
  for (int k = 0; k < 4; ++k) {
    int4 v = p[k];
    w |= (unsigned)(v.x != 0) << (k * 4 + 0);
    w |= (unsigned)(v.y != 0) << (k * 4 + 1);
    w |= (unsigned)(v.z != 0) << (k * 4 + 2);
    w |= (unsigned)(v.w != 0) << (k * 4 + 3);
  }
  outw[i] = (u16)w;
}

__global__ __launch_bounds__(256) void cvt_f32_f16(
    const float* __restrict__ in, u16* __restrict__ outp, int n4)
{
  const int i = blockIdx.x * 256 + threadIdx.x;
  if (i >= n4) return;
  float4 v = ((const float4*)in)[i];
  u16x4 o; o[0] = f2h(v.x); o[1] = f2h(v.y); o[2] = f2h(v.z); o[3] = f2h(v.w);
  ((u16x4*)outp)[i] = o;
}

__global__ __launch_bounds__(256) void transpose_cvt(
    const float* __restrict__ in, u16* __restrict__ outp, int R, int C)
{
  const int idx = blockIdx.x * 256 + threadIdx.x;
  const int i = idx / C, j = idx % C;
  outp[(size_t)j * R + i] = f2h(in[idx]);
}

// ---------------------------------------------------------------------------
extern "C" void kernel_launch(void* const* d_in, const int* in_sizes, int n_in,
                              void* d_out, int out_size, void* d_ws, size_t ws_size,
                              hipStream_t stream) {
  (void)in_sizes; (void)n_in; (void)out_size;
  const float* x    = (const float*)d_in[0];
  const int*   adj  = (const int*)d_in[1];
  const float* W    = (const float*)d_in[2];
  const float* bvec = (const float*)d_in[3];
  const float* attn = (const float*)d_in[4];
  float* out = (float*)d_out;

  constexpr int B = 8, N = 2048, D = 512;
  constexpr size_t MN = (size_t)B * N;  // 16384

  char* ws = (char*)d_ws;
  size_t off = 0;
  auto take = [&](size_t bytes) -> char* {
    char* p = ws + off;
    off += (bytes + 255) & ~(size_t)255;
    return p;
  };
  u16* xh   = (u16*)take(MN * D * 2);
  u16* Wh   = (u16*)take((size_t)D * D * 2);
  u16* attT = (u16*)take((size_t)D * D * 2);
  u16* h    = (u16*)take(MN * D * 2);
  u16* hT   = (u16*)take(MN * D * 2);
  u16* ha   = (u16*)take(MN * D * 2);
  u16* adjb = (u16*)take((size_t)B * N * (N / 16) * 2);  // 4 MB
  if (off > ws_size) return;

  // converts + adjacency pack
  cvt_f32_f16<<<dim3((unsigned)(MN * D / 4 / 256)), 256, 0, stream>>>(x, xh, (int)(MN * D / 4));
  cvt_f32_f16<<<dim3(D * D / 4 / 256), 256, 0, stream>>>(W, Wh, D * D / 4);
  transpose_cvt<<<dim3(D * D / 256), 256, 0, stream>>>(attn, attT, D, D);
  const int nwords = (int)(MN * (N / 16));
  adj_pack<<<dim3(nwords / 256), 256, 0, stream>>>(adj, adjb, nwords);

  // K1: h = xh . Wh^T + bias (also writes hT)
  gemm_bt<3><<<dim3(D / 128, MN / 128), 256, 0, stream>>>(
      xh, Wh, h, bvec, hT, D, D);
  // K2: ha = h . attT^T
  gemm_bt<0><<<dim3(D / 128, MN / 128), 256, 0, stream>>>(
      h, attT, ha, nullptr, nullptr, D, D);

  // fused S -> masked softmax -> PV -> elu
  flash_gat<<<dim3(512), 512, 0, stream>>>(ha, h, hT, adjb, out);
}